// Round 2
// 672.372 us; speedup vs baseline: 2.0674x; 2.0674x over previous
//
#include <hip/hip_runtime.h>
#include <stdint.h>

// ---------------- common helpers ----------------

typedef __attribute__((ext_vector_type(8))) short frag8;   // 8 bf16 (4 VGPRs), MFMA A/B operand
typedef __attribute__((ext_vector_type(4))) float frag4f;  // 4 fp32, MFMA C/D operand

__device__ __forceinline__ uint16_t f2bf(float f) {
  union { float f; uint32_t i; } x; x.f = f;
  uint32_t r = x.i + 0x7fffu + ((x.i >> 16) & 1u);  // round-to-nearest-even
  return (uint16_t)(r >> 16);
}

// ---------------- kernel 0: fp32 -> bf16 conversion (RTNE), vectorized ----------------

__global__ __launch_bounds__(256)
void k_cvt(const float* __restrict__ src, uint16_t* __restrict__ dst, int n4, int ok)
{
  if (!ok) return;
  int i = blockIdx.x * 256 + threadIdx.x;
  const int stride = gridDim.x * 256;
  for (; i < n4; i += stride) {
    float4 v = ((const float4*)src)[i];
    ushort4 o;
    o.x = f2bf(v.x); o.y = f2bf(v.y); o.z = f2bf(v.z); o.w = f2bf(v.w);
    ((ushort4*)dst)[i] = o;
  }
}

// ---------------- kernel 1: fused roll + QKV GEMM + windowed attention ----------------
// grid: 512 M-tiles (128 rows = 8 batches) x 16 heads = 8192 blocks, 256 threads.
// Inputs: bf16 copies of x / w_qkv in ws; fp32 b_qkv / rel_pos direct.
// Output: bf16 attn (65536 x 1024) written into d_out's bytes (exact fit).

struct SmemGemm { uint16_t A[128 * 32]; uint16_t B[192 * 32]; };              // 8 KB + 12 KB
struct SmemEpi  { uint16_t q[128][72]; uint16_t k[128][72];                    // 18 KB x2
                  uint16_t vT[64][136]; uint16_t p[8][16][24]; };              // 17 KB + 6 KB
union Smem1 { SmemGemm s; SmemEpi e; };                                        // 59 KB -> 2 blocks/CU

__global__ __launch_bounds__(256, 2)
void k_qkv_attn(const uint16_t* __restrict__ xb, const uint16_t* __restrict__ wqkvb,
                const float* __restrict__ b_qkv, const float* __restrict__ rel_pos,
                uint16_t* __restrict__ attn16, int ws_ok)
{
  __shared__ Smem1 sm;
  const int bid  = blockIdx.x;
  const int h    = bid & 15;
  const int mt   = bid >> 4;
  const int t    = threadIdx.x;
  const int lane = t & 63;
  const int wv   = t >> 6;
  const int l15  = lane & 15;
  const int quad = lane >> 4;
  const int wr   = wv & 1;
  const int wc   = wv >> 1;

  if (!ws_ok) {  // ws too small: write zero attn slice (diagnostic), touch no ws
    #pragma unroll
    for (int i = 0; i < 32; ++i) {
      const int local = t + 256 * i;           // 0..8191
      const int row = local >> 6, col = local & 63;
      attn16[(mt * 128 + row) * 1024 + h * 64 + col] = 0;
    }
    return;
  }

  // A staging: roll(-8 tokens within each batch of 16) folded into source row.
  const int arow0 = t >> 2, aoff = t & 3;
  const int g0 = mt * 128 + arow0;
  const int g1 = g0 + 64;
  const int asrc0 = (((g0 & ~15) | ((g0 + 8) & 15)) * 512) + aoff * 8;
  const int asrc1 = (((g1 & ~15) | ((g1 + 8) & 15)) * 512) + aoff * 8;
  int bsrc[3];
  #pragma unroll
  for (int i = 0; i < 3; ++i) {
    int c = t + 256 * i;
    int brow = c >> 2;  // 0..191
    int gc = (brow < 64) ? (h * 64 + brow)
           : (brow < 128) ? (1024 + h * 64 + (brow - 64))
                          : (2048 + h * 64 + (brow - 128));
    bsrc[i] = gc * 512 + (c & 3) * 8;
  }

  frag4f acc[4][6];
  #pragma unroll
  for (int a = 0; a < 4; ++a)
    #pragma unroll
    for (int b = 0; b < 6; ++b) acc[a][b] = (frag4f)0.0f;

  for (int kk = 0; kk < 16; ++kk) {
    const int kb = kk * 32;
    uint4 va0 = *(const uint4*)(xb + asrc0 + kb);
    uint4 va1 = *(const uint4*)(xb + asrc1 + kb);
    uint4 vb0 = *(const uint4*)(wqkvb + bsrc[0] + kb);
    uint4 vb1 = *(const uint4*)(wqkvb + bsrc[1] + kb);
    uint4 vb2 = *(const uint4*)(wqkvb + bsrc[2] + kb);
    __syncthreads();
    *(uint4*)&sm.s.A[t * 8]         = va0;
    *(uint4*)&sm.s.A[(t + 256) * 8] = va1;
    *(uint4*)&sm.s.B[t * 8]         = vb0;
    *(uint4*)&sm.s.B[(t + 256) * 8] = vb1;
    *(uint4*)&sm.s.B[(t + 512) * 8] = vb2;
    __syncthreads();
    frag8 af[4], bf[6];
    #pragma unroll
    for (int rt = 0; rt < 4; ++rt)
      af[rt] = *(const frag8*)&sm.s.A[(wr * 64 + rt * 16 + l15) * 32 + quad * 8];
    #pragma unroll
    for (int ct = 0; ct < 6; ++ct)
      bf[ct] = *(const frag8*)&sm.s.B[((wc * 6 + ct) * 16 + l15) * 32 + quad * 8];
    #pragma unroll
    for (int rt = 0; rt < 4; ++rt)
      #pragma unroll
      for (int ct = 0; ct < 6; ++ct)
        acc[rt][ct] = __builtin_amdgcn_mfma_f32_16x16x32_bf16(af[rt], bf[ct], acc[rt][ct], 0, 0, 0);
  }
  __syncthreads();  // staging LDS dead; epilogue aliases it

  // ---- epilogue: +bias (fp32), stage Q, K row-major and V transposed ----
  #pragma unroll
  for (int ct = 0; ct < 6; ++ct) {
    const int C = (wc * 6 + ct) * 16 + l15;  // 0..191
    const int gc = (C < 64) ? (h * 64 + C)
                 : (C < 128) ? (1024 + h * 64 + (C - 64))
                             : (2048 + h * 64 + (C - 128));
    const float bias = b_qkv[gc];
    #pragma unroll
    for (int rt = 0; rt < 4; ++rt) {
      #pragma unroll
      for (int r = 0; r < 4; ++r) {
        const int row = wr * 64 + rt * 16 + quad * 4 + r;  // C-layout: row=quad*4+reg, col=l15
        const uint16_t val = f2bf(acc[rt][ct][r] + bias);
        if (C < 64)       sm.e.q[row][C] = val;
        else if (C < 128) sm.e.k[row][C - 64] = val;
        else              sm.e.vT[C - 128][row] = val;
      }
    }
  }
  __syncthreads();

  // ---- attention: wave wv handles windows {2wv, 2wv+1} ----
  const float scl = 0.125f;  // 64^-0.5
  #pragma unroll
  for (int bbi = 0; bbi < 2; ++bbi) {
    const int bb = wv * 2 + bbi;
    frag8 a0 = *(const frag8*)&sm.e.q[bb * 16 + l15][quad * 8];
    frag8 a1 = *(const frag8*)&sm.e.q[bb * 16 + l15][32 + quad * 8];
    frag8 b0 = *(const frag8*)&sm.e.k[bb * 16 + l15][quad * 8];
    frag8 b1 = *(const frag8*)&sm.e.k[bb * 16 + l15][32 + quad * 8];
    frag4f s = (frag4f)0.0f;
    s = __builtin_amdgcn_mfma_f32_16x16x32_bf16(a0, b0, s, 0, 0, 0);
    s = __builtin_amdgcn_mfma_f32_16x16x32_bf16(a1, b1, s, 0, 0, 0);
    const int j = l15;
    #pragma unroll
    for (int r = 0; r < 4; ++r) {
      const int i = quad * 4 + r;
      const int r0 = (i >> 2) - (j >> 2) + 3;
      const int r1 = (i & 3) - (j & 3) + 3;
      const float bias = rel_pos[h * 49 + r0 * 7 + r1];
      const bool msk = ((h >= 14) && (((i >> 2) < 2) != ((j >> 2) < 2))) ||
                       ((h & 1)  && (((i & 3) < 2) != ((j & 3) < 2)));
      float v = msk ? -1e30f : (s[r] * scl + bias);
      float m = v;
      m = fmaxf(m, __shfl_xor(m, 1));
      m = fmaxf(m, __shfl_xor(m, 2));
      m = fmaxf(m, __shfl_xor(m, 4));
      m = fmaxf(m, __shfl_xor(m, 8));
      float e = __expf(v - m);
      float su = e;
      su += __shfl_xor(su, 1);
      su += __shfl_xor(su, 2);
      su += __shfl_xor(su, 4);
      su += __shfl_xor(su, 8);
      sm.e.p[bb][i][j] = f2bf(e / su);
    }
  }
  __syncthreads();

  // ---- O = P V; K=32 MFMA with k>=16 half of A zeroed ----
  #pragma unroll
  for (int bbi = 0; bbi < 2; ++bbi) {
    const int bb = wv * 2 + bbi;
    frag8 ap;
    if (quad < 2) ap = *(const frag8*)&sm.e.p[bb][l15][quad * 8];
    else          ap = (frag8)0;
    #pragma unroll
    for (int dt = 0; dt < 4; ++dt) {
      frag8 bv = *(const frag8*)&sm.e.vT[dt * 16 + l15][bb * 16 + (quad & 1) * 8];
      frag4f o = (frag4f)0.0f;
      o = __builtin_amdgcn_mfma_f32_16x16x32_bf16(ap, bv, o, 0, 0, 0);
      #pragma unroll
      for (int r = 0; r < 4; ++r) {
        const int grow = mt * 128 + bb * 16 + quad * 4 + r;
        attn16[grow * 1024 + h * 64 + dt * 16 + l15] = f2bf(o[r]);
      }
    }
  }
}

// ---------------- kernel 2: projection GEMM (M=65536, K=1024, N=512) + bias, fp32 out ----------------
// In-place constraint: out fp32 row r occupies the same 2048 bytes as attn16 bf16
// row r, so a block must own COMPLETE rows (read all K before writing any col).
// Structure (m97-style): grid 1024 blocks x 512 threads (8 waves).
// Tile = 64 rows x all 512 cols, BK=32, 32 K-steps.
//  - A tile 64x32 (4 KB) + B tile 512x32 (32 KB) staged via global_load_lds
//    width-16 (no VGPR round-trip -> no spill), double-buffered (72 KB LDS).
//  - 2-phase pipeline: issue next tile's loads, compute current, one
//    __syncthreads per K-step (its vmcnt(0)+lgkmcnt(0) drain is exactly the
//    wait we need: next buffer ready + all waves done reading current).
//  - wave wv owns cols [wv*64, wv*64+64): acc 4x4 frag4f = 64 AGPR.
// In-place safety: all global A reads complete before the final barrier of the
// last K-step; epilogue stores happen after it. Blocks touch only their rows.

__global__ __launch_bounds__(512, 4)
void k_proj(const uint16_t* __restrict__ attn16, const uint16_t* __restrict__ wprojb,
            const float* __restrict__ b_proj, float* __restrict__ out, int ws_ok)
{
  __shared__ uint8_t smraw[2 * 36864];  // 2 x (A 4096 B + B 32768 B) = 72 KB
  const int mt   = blockIdx.x;          // 0..1023, rows [mt*64, mt*64+64)
  const int t    = threadIdx.x;
  const int lane = t & 63;
  const int wv   = t >> 6;              // 0..7
  const int l15  = lane & 15;
  const int quad = lane >> 4;

  if (!ws_ok) {  // diagnostic fallback: bias only
    for (int i = t; i < 64 * 512; i += 512) {
      const int row = i >> 9, col = i & 511;
      out[(mt * 64 + row) * 512 + col] = b_proj[col];
    }
    return;
  }

  // ---- staging map: 36 chunks of 1 KB (64 lanes x 16 B). Chunks 0..3 = A
  // (64 rows x 64 B), chunks 4..35 = B (512 rows x 64 B). Wave wv stages
  // cnt chunks starting at c0. Per-lane global base (element offset sans kk).
  const int cnt = (wv < 4) ? 5 : 4;
  const int c0  = (wv < 4) ? wv * 5 : 20 + (wv - 4) * 4;

  const uint16_t* gp[5];
  int lds_off[5];
  #pragma unroll
  for (int o = 0; o < 5; ++o) {
    int c = c0 + o;
    if (c > 35) c = 35;                          // clamp unused slot (never issued)
    const int e = c * 512 + lane * 8;            // element index in the 36 KB tile
    if (e < 2048) {                              // A region: row = e/32
      gp[o] = attn16 + (size_t)(mt * 64 + (e >> 5)) * 1024 + (e & 31);
    } else {                                     // B region: col = (e-2048)/32
      const int eb = e - 2048;
      gp[o] = wprojb + (size_t)(eb >> 5) * 1024 + (eb & 31);
    }
    lds_off[o] = (c0 + o) * 1024;
  }

  frag4f acc[4][4];
  #pragma unroll
  for (int a = 0; a < 4; ++a)
    #pragma unroll
    for (int b = 0; b < 4; ++b) acc[a][b] = (frag4f)0.0f;

  auto STAGE = [&](int buf, int kk) {
    #pragma unroll
    for (int o = 0; o < 5; ++o)
      if (o < cnt)
        __builtin_amdgcn_global_load_lds(
            (const __attribute__((address_space(1))) void*)(gp[o] + kk * 32),
            (__attribute__((address_space(3))) void*)(smraw + buf * 36864 + lds_off[o]),
            16, 0, 0);
  };

  STAGE(0, 0);
  __syncthreads();  // drains vmcnt(0): buf0 ready

  for (int kk = 0; kk < 32; ++kk) {
    const int cur = kk & 1;
    if (kk < 31) STAGE(cur ^ 1, kk + 1);  // issue next tile; flies under compute

    const uint16_t* As = (const uint16_t*)(smraw + cur * 36864);
    const uint16_t* Bs = (const uint16_t*)(smraw + cur * 36864 + 4096);
    frag8 af[4];
    #pragma unroll
    for (int rt = 0; rt < 4; ++rt)
      af[rt] = *(const frag8*)(As + (rt * 16 + l15) * 32 + quad * 8);
    #pragma unroll
    for (int ct = 0; ct < 4; ++ct) {
      frag8 bfr = *(const frag8*)(Bs + (wv * 64 + ct * 16 + l15) * 32 + quad * 8);
      #pragma unroll
      for (int rt = 0; rt < 4; ++rt)
        acc[rt][ct] = __builtin_amdgcn_mfma_f32_16x16x32_bf16(af[rt], bfr, acc[rt][ct], 0, 0, 0);
    }
    __syncthreads();  // vmcnt(0): next buf ready; all waves done reading cur
  }

  // ---- epilogue: + bias, fp32 stores (after final barrier -> all A reads done)
  #pragma unroll
  for (int ct = 0; ct < 4; ++ct) {
    const int gcol = wv * 64 + ct * 16 + l15;
    const float bias = b_proj[gcol];
    #pragma unroll
    for (int rt = 0; rt < 4; ++rt) {
      #pragma unroll
      for (int r = 0; r < 4; ++r) {
        const int grow = mt * 64 + rt * 16 + quad * 4 + r;  // C-layout: row=quad*4+reg
        out[grow * 512 + gcol] = acc[rt][ct][r] + bias;
      }
    }
  }
}

// ---------------- launch ----------------

extern "C" void kernel_launch(void* const* d_in, const int* in_sizes, int n_in,
                              void* d_out, int out_size, void* d_ws, size_t ws_size,
                              hipStream_t stream) {
  const float* x      = (const float*)d_in[0];   // (4096,16,512) fp32
  const float* w_qkv  = (const float*)d_in[1];   // (3072,512)    fp32
  const float* b_qkv  = (const float*)d_in[2];   // (3072,)       fp32
  const float* w_proj = (const float*)d_in[3];   // (512,1024)    fp32
  const float* b_proj = (const float*)d_in[4];   // (512,)        fp32
  const float* rel    = (const float*)d_in[5];   // (16,7,7)      fp32

  // ws layout (bf16): x 33,554,432 | w_qkv 1,572,864 | w_proj 524,288 el
  uint16_t* xb     = (uint16_t*)d_ws;
  uint16_t* wqkvb  = xb + 33554432;
  uint16_t* wprojb = wqkvb + 1572864;
  const size_t ws_need = (size_t)(33554432 + 1572864 + 524288) * 2;
  const int ws_ok = (ws_size >= ws_need) ? 1 : 0;

  // d_out bytes: phase 1 = bf16 attn (65536 x 1024 x 2B), phase 2 = fp32 out (65536 x 512 x 4B)
  uint16_t* attn16 = (uint16_t*)d_out;
  float*    out    = (float*)d_out;

  k_cvt<<<dim3(4096), dim3(256), 0, stream>>>(x,      xb,     33554432 / 4, ws_ok);
  k_cvt<<<dim3(1536), dim3(256), 0, stream>>>(w_qkv,  wqkvb,  1572864 / 4,  ws_ok);
  k_cvt<<<dim3(512),  dim3(256), 0, stream>>>(w_proj, wprojb, 524288 / 4,   ws_ok);
  k_qkv_attn<<<dim3(512 * 16), dim3(256), 0, stream>>>(xb, wqkvb, b_qkv, rel, attn16, ws_ok);
  k_proj    <<<dim3(1024),     dim3(512), 0, stream>>>(attn16, wprojb, b_proj, out, ws_ok);
}

// Round 3
// 633.728 us; speedup vs baseline: 2.1935x; 1.0610x over previous
//
#include <hip/hip_runtime.h>
#include <stdint.h>

// ---------------- common helpers ----------------

typedef __attribute__((ext_vector_type(8))) short frag8;   // 8 bf16 (4 VGPRs), MFMA A/B operand
typedef __attribute__((ext_vector_type(4))) float frag4f;  // 4 fp32, MFMA C/D operand

__device__ __forceinline__ uint16_t f2bf(float f) {
  union { float f; uint32_t i; } x; x.f = f;
  uint32_t r = x.i + 0x7fffu + ((x.i >> 16) & 1u);  // round-to-nearest-even
  return (uint16_t)(r >> 16);
}

// ---------------- kernel 0: fp32 -> bf16 conversion (RTNE), vectorized ----------------

__global__ __launch_bounds__(256)
void k_cvt(const float* __restrict__ src, uint16_t* __restrict__ dst, int n4, int ok)
{
  if (!ok) return;
  int i = blockIdx.x * 256 + threadIdx.x;
  const int stride = gridDim.x * 256;
  for (; i < n4; i += stride) {
    float4 v = ((const float4*)src)[i];
    ushort4 o;
    o.x = f2bf(v.x); o.y = f2bf(v.y); o.z = f2bf(v.z); o.w = f2bf(v.w);
    ((ushort4*)dst)[i] = o;
  }
}

// ---------------- kernel 1: fused roll + QKV GEMM + windowed attention ----------------
// grid: 512 M-tiles (128 rows = 8 batches) x 16 heads = 8192 blocks, 256 threads.
// GEMM staging now: global_load_lds width-16, double-buffered, 2-phase, with a
// both-sides XOR slot swizzle (slot' = slot ^ ((row>>1)&3), applied on the
// global SOURCE address and on the LDS READ; LDS dest stays linear) -> A/B
// fragment ds_read_b128 are bank-conflict-free (lanes 0..7 hit 8 distinct
// bank quads instead of 2).
// Tile layout in LDS (per buffer, 20 KB): A 128 rows x 32 k (8 KB, rows of
// 64 B = 4 slots of 16 B), then B 192 cols x 32 k (12 KB).

struct SmemEpi  { uint16_t q[128][72]; uint16_t k[128][72];                    // 18 KB x2
                  uint16_t vT[64][136]; uint16_t p[8][16][24]; };              // 17 KB + 6 KB
union Smem1 { uint8_t g[2][20480]; SmemEpi e; };                               // 59 KB -> 2 blocks/CU

__global__ __launch_bounds__(256, 2)
void k_qkv_attn(const uint16_t* __restrict__ xb, const uint16_t* __restrict__ wqkvb,
                const float* __restrict__ b_qkv, const float* __restrict__ rel_pos,
                uint16_t* __restrict__ attn16, int ws_ok)
{
  __shared__ Smem1 sm;
  const int bid  = blockIdx.x;
  const int h    = bid & 15;
  const int mt   = bid >> 4;
  const int t    = threadIdx.x;
  const int lane = t & 63;
  const int wv   = t >> 6;
  const int l15  = lane & 15;
  const int quad = lane >> 4;
  const int wr   = wv & 1;
  const int wc   = wv >> 1;

  if (!ws_ok) {  // ws too small: write zero attn slice (diagnostic), touch no ws
    #pragma unroll
    for (int i = 0; i < 32; ++i) {
      const int local = t + 256 * i;           // 0..8191
      const int row = local >> 6, col = local & 63;
      attn16[(mt * 128 + row) * 1024 + h * 64 + col] = 0;
    }
    return;
  }

  // ---- staging map: 20 chunks of 1 KB (64 lanes x 16 B). Chunks 0..7 = A
  // (128 rows x 64 B), chunks 8..19 = B (192 cols x 64 B). Wave wv stages 5
  // chunks. Within each 64 B row the 4 16-B slots are stored XOR-permuted:
  // LDS slot s' holds global slot s = s' ^ ((row>>1)&3). On the source side
  // that is the per-lane constant slot_g below (row = c*16 + (lane>>2)).
  const int slot_g = (lane & 3) ^ ((lane >> 3) & 3);
  const uint16_t* sp[5];
  int ldsoff[5];
  #pragma unroll
  for (int o = 0; o < 5; ++o) {
    const int c = wv * 5 + o;                  // 0..19
    const int rloc = c * 16 + (lane >> 2);     // tile-local row/col index
    if (c < 8) {                               // A: roll(-8 within 16) folded in
      const int g = mt * 128 + rloc;
      const int srow = (g & ~15) | ((g + 8) & 15);
      sp[o] = xb + srow * 512 + slot_g * 8;
    } else {                                   // B: q/k/v thirds of head h
      const int cb = rloc - 128;               // 0..191
      const int gc = (cb < 64) ? (h * 64 + cb)
                   : (cb < 128) ? (1024 + h * 64 + (cb - 64))
                                : (2048 + h * 64 + (cb - 128));
      sp[o] = wqkvb + gc * 512 + slot_g * 8;
    }
    ldsoff[o] = c * 1024;
  }

  frag4f acc[4][6];
  #pragma unroll
  for (int a = 0; a < 4; ++a)
    #pragma unroll
    for (int b = 0; b < 6; ++b) acc[a][b] = (frag4f)0.0f;

  auto STAGE = [&](int buf, int kk) {
    #pragma unroll
    for (int o = 0; o < 5; ++o)
      __builtin_amdgcn_global_load_lds(
          (const __attribute__((address_space(1))) void*)(sp[o] + kk * 32),
          (__attribute__((address_space(3))) void*)(sm.g[buf] + ldsoff[o]),
          16, 0, 0);
  };

  STAGE(0, 0);
  __syncthreads();  // vmcnt(0): buf0 ready

  const int xq = quad ^ ((l15 >> 1) & 3);  // swizzled read slot
  for (int kk = 0; kk < 16; ++kk) {
    const int cur = kk & 1;
    if (kk < 15) STAGE(cur ^ 1, kk + 1);   // next tile flies under compute

    const uint8_t* base = sm.g[cur];
    frag8 af[4], bf[6];
    #pragma unroll
    for (int rt = 0; rt < 4; ++rt)
      af[rt] = *(const frag8*)(base + (wr * 64 + rt * 16 + l15) * 64 + xq * 16);
    #pragma unroll
    for (int ct = 0; ct < 6; ++ct)
      bf[ct] = *(const frag8*)(base + 8192 + ((wc * 6 + ct) * 16 + l15) * 64 + xq * 16);
    #pragma unroll
    for (int rt = 0; rt < 4; ++rt)
      #pragma unroll
      for (int ct = 0; ct < 6; ++ct)
        acc[rt][ct] = __builtin_amdgcn_mfma_f32_16x16x32_bf16(af[rt], bf[ct], acc[rt][ct], 0, 0, 0);
    __syncthreads();  // next buf ready; all waves done reading cur; last iter: staging LDS dead
  }

  // ---- epilogue: +bias (fp32), stage Q, K row-major and V transposed ----
  #pragma unroll
  for (int ct = 0; ct < 6; ++ct) {
    const int C = (wc * 6 + ct) * 16 + l15;  // 0..191
    const int gc = (C < 64) ? (h * 64 + C)
                 : (C < 128) ? (1024 + h * 64 + (C - 64))
                             : (2048 + h * 64 + (C - 128));
    const float bias = b_qkv[gc];
    #pragma unroll
    for (int rt = 0; rt < 4; ++rt) {
      #pragma unroll
      for (int r = 0; r < 4; ++r) {
        const int row = wr * 64 + rt * 16 + quad * 4 + r;  // C-layout: row=quad*4+reg, col=l15
        const uint16_t val = f2bf(acc[rt][ct][r] + bias);
        if (C < 64)       sm.e.q[row][C] = val;
        else if (C < 128) sm.e.k[row][C - 64] = val;
        else              sm.e.vT[C - 128][row] = val;
      }
    }
  }
  __syncthreads();

  // ---- attention: wave wv handles windows {2wv, 2wv+1} ----
  const float scl = 0.125f;  // 64^-0.5
  #pragma unroll
  for (int bbi = 0; bbi < 2; ++bbi) {
    const int bb = wv * 2 + bbi;
    frag8 a0 = *(const frag8*)&sm.e.q[bb * 16 + l15][quad * 8];
    frag8 a1 = *(const frag8*)&sm.e.q[bb * 16 + l15][32 + quad * 8];
    frag8 b0 = *(const frag8*)&sm.e.k[bb * 16 + l15][quad * 8];
    frag8 b1 = *(const frag8*)&sm.e.k[bb * 16 + l15][32 + quad * 8];
    frag4f s = (frag4f)0.0f;
    s = __builtin_amdgcn_mfma_f32_16x16x32_bf16(a0, b0, s, 0, 0, 0);
    s = __builtin_amdgcn_mfma_f32_16x16x32_bf16(a1, b1, s, 0, 0, 0);
    const int j = l15;
    #pragma unroll
    for (int r = 0; r < 4; ++r) {
      const int i = quad * 4 + r;
      const int r0 = (i >> 2) - (j >> 2) + 3;
      const int r1 = (i & 3) - (j & 3) + 3;
      const float bias = rel_pos[h * 49 + r0 * 7 + r1];
      const bool msk = ((h >= 14) && (((i >> 2) < 2) != ((j >> 2) < 2))) ||
                       ((h & 1)  && (((i & 3) < 2) != ((j & 3) < 2)));
      float v = msk ? -1e30f : (s[r] * scl + bias);
      float m = v;
      m = fmaxf(m, __shfl_xor(m, 1));
      m = fmaxf(m, __shfl_xor(m, 2));
      m = fmaxf(m, __shfl_xor(m, 4));
      m = fmaxf(m, __shfl_xor(m, 8));
      float e = __expf(v - m);
      float su = e;
      su += __shfl_xor(su, 1);
      su += __shfl_xor(su, 2);
      su += __shfl_xor(su, 4);
      su += __shfl_xor(su, 8);
      sm.e.p[bb][i][j] = f2bf(e / su);
    }
  }
  __syncthreads();

  // ---- O = P V; K=32 MFMA with k>=16 half of A zeroed ----
  #pragma unroll
  for (int bbi = 0; bbi < 2; ++bbi) {
    const int bb = wv * 2 + bbi;
    frag8 ap;
    if (quad < 2) ap = *(const frag8*)&sm.e.p[bb][l15][quad * 8];
    else          ap = (frag8)0;
    #pragma unroll
    for (int dt = 0; dt < 4; ++dt) {
      frag8 bv = *(const frag8*)&sm.e.vT[dt * 16 + l15][bb * 16 + (quad & 1) * 8];
      frag4f o = (frag4f)0.0f;
      o = __builtin_amdgcn_mfma_f32_16x16x32_bf16(ap, bv, o, 0, 0, 0);
      #pragma unroll
      for (int r = 0; r < 4; ++r) {
        const int grow = mt * 128 + bb * 16 + quad * 4 + r;
        attn16[grow * 1024 + h * 64 + dt * 16 + l15] = f2bf(o[r]);
      }
    }
  }
}

// ---------------- kernel 2: projection GEMM (M=65536, K=1024, N=512) + bias, fp32 out ----------------
// In-place constraint: out fp32 row r occupies the same 2048 bytes as attn16 bf16
// row r, so a block must own COMPLETE rows (read all K before writing any col).
// Structure: grid 1024 blocks x 512 threads (8 waves), tile 64 rows x 512 cols,
// BK=32, global_load_lds dbuf 2-phase. Same XOR slot swizzle as k_qkv_attn
// (source-permuted writes + permuted reads) for conflict-free ds_read_b128.

__global__ __launch_bounds__(512, 4)
void k_proj(const uint16_t* __restrict__ attn16, const uint16_t* __restrict__ wprojb,
            const float* __restrict__ b_proj, float* __restrict__ out, int ws_ok)
{
  __shared__ uint8_t smraw[2 * 36864];  // 2 x (A 4096 B + B 32768 B) = 72 KB
  const int mt   = blockIdx.x;          // 0..1023, rows [mt*64, mt*64+64)
  const int t    = threadIdx.x;
  const int lane = t & 63;
  const int wv   = t >> 6;              // 0..7
  const int l15  = lane & 15;
  const int quad = lane >> 4;

  if (!ws_ok) {  // diagnostic fallback: bias only
    for (int i = t; i < 64 * 512; i += 512) {
      const int row = i >> 9, col = i & 511;
      out[(mt * 64 + row) * 512 + col] = b_proj[col];
    }
    return;
  }

  // ---- staging map: 36 chunks of 1 KB. Chunks 0..3 = A (64 rows x 64 B),
  // chunks 4..35 = B (512 cols x 64 B). XOR slot swizzle on the source side.
  const int cnt = (wv < 4) ? 5 : 4;
  const int c0  = (wv < 4) ? wv * 5 : 20 + (wv - 4) * 4;
  const int slot_g = (lane & 3) ^ ((lane >> 3) & 3);

  const uint16_t* gp[5];
  int lds_off[5];
  #pragma unroll
  for (int o = 0; o < 5; ++o) {
    int c = c0 + o;
    if (c > 35) c = 35;                          // clamp unused slot (never issued)
    const int rloc = c * 16 + (lane >> 2);       // tile-local row/col
    if (c < 4) {                                 // A region: rows 0..63
      gp[o] = attn16 + (size_t)(mt * 64 + rloc) * 1024 + slot_g * 8;
    } else {                                     // B region: cols 0..511
      gp[o] = wprojb + (size_t)(rloc - 64) * 1024 + slot_g * 8;
    }
    lds_off[o] = (c0 + o) * 1024;
  }

  frag4f acc[4][4];
  #pragma unroll
  for (int a = 0; a < 4; ++a)
    #pragma unroll
    for (int b = 0; b < 4; ++b) acc[a][b] = (frag4f)0.0f;

  auto STAGE = [&](int buf, int kk) {
    #pragma unroll
    for (int o = 0; o < 5; ++o)
      if (o < cnt)
        __builtin_amdgcn_global_load_lds(
            (const __attribute__((address_space(1))) void*)(gp[o] + kk * 32),
            (__attribute__((address_space(3))) void*)(smraw + buf * 36864 + lds_off[o]),
            16, 0, 0);
  };

  STAGE(0, 0);
  __syncthreads();  // drains vmcnt(0): buf0 ready

  const int xq = quad ^ ((l15 >> 1) & 3);  // swizzled read slot
  for (int kk = 0; kk < 32; ++kk) {
    const int cur = kk & 1;
    if (kk < 31) STAGE(cur ^ 1, kk + 1);  // issue next tile; flies under compute

    const uint16_t* As = (const uint16_t*)(smraw + cur * 36864);
    const uint16_t* Bs = (const uint16_t*)(smraw + cur * 36864 + 4096);
    frag8 af[4];
    #pragma unroll
    for (int rt = 0; rt < 4; ++rt)
      af[rt] = *(const frag8*)(As + (rt * 16 + l15) * 32 + xq * 8);
    #pragma unroll
    for (int ct = 0; ct < 4; ++ct) {
      frag8 bfr = *(const frag8*)(Bs + (wv * 64 + ct * 16 + l15) * 32 + xq * 8);
      #pragma unroll
      for (int rt = 0; rt < 4; ++rt)
        acc[rt][ct] = __builtin_amdgcn_mfma_f32_16x16x32_bf16(af[rt], bfr, acc[rt][ct], 0, 0, 0);
    }
    __syncthreads();  // vmcnt(0): next buf ready; all waves done reading cur
  }

  // ---- epilogue: + bias, fp32 stores (after final barrier -> all A reads done)
  #pragma unroll
  for (int ct = 0; ct < 4; ++ct) {
    const int gcol = wv * 64 + ct * 16 + l15;
    const float bias = b_proj[gcol];
    #pragma unroll
    for (int rt = 0; rt < 4; ++rt) {
      #pragma unroll
      for (int r = 0; r < 4; ++r) {
        const int grow = mt * 64 + rt * 16 + quad * 4 + r;  // C-layout: row=quad*4+reg
        out[grow * 512 + gcol] = acc[rt][ct][r] + bias;
      }
    }
  }
}

// ---------------- launch ----------------

extern "C" void kernel_launch(void* const* d_in, const int* in_sizes, int n_in,
                              void* d_out, int out_size, void* d_ws, size_t ws_size,
                              hipStream_t stream) {
  const float* x      = (const float*)d_in[0];   // (4096,16,512) fp32
  const float* w_qkv  = (const float*)d_in[1];   // (3072,512)    fp32
  const float* b_qkv  = (const float*)d_in[2];   // (3072,)       fp32
  const float* w_proj = (const float*)d_in[3];   // (512,1024)    fp32
  const float* b_proj = (const float*)d_in[4];   // (512,)        fp32
  const float* rel    = (const float*)d_in[5];   // (16,7,7)      fp32

  // ws layout (bf16): x 33,554,432 | w_qkv 1,572,864 | w_proj 524,288 el
  uint16_t* xb     = (uint16_t*)d_ws;
  uint16_t* wqkvb  = xb + 33554432;
  uint16_t* wprojb = wqkvb + 1572864;
  const size_t ws_need = (size_t)(33554432 + 1572864 + 524288) * 2;
  const int ws_ok = (ws_size >= ws_need) ? 1 : 0;

  // d_out bytes: phase 1 = bf16 attn (65536 x 1024 x 2B), phase 2 = fp32 out (65536 x 512 x 4B)
  uint16_t* attn16 = (uint16_t*)d_out;
  float*    out    = (float*)d_out;

  k_cvt<<<dim3(4096), dim3(256), 0, stream>>>(x,      xb,     33554432 / 4, ws_ok);
  k_cvt<<<dim3(1536), dim3(256), 0, stream>>>(w_qkv,  wqkvb,  1572864 / 4,  ws_ok);
  k_cvt<<<dim3(512),  dim3(256), 0, stream>>>(w_proj, wprojb, 524288 / 4,   ws_ok);
  k_qkv_attn<<<dim3(512 * 16), dim3(256), 0, stream>>>(xb, wqkvb, b_qkv, rel, attn16, ws_ok);
  k_proj    <<<dim3(1024),     dim3(512), 0, stream>>>(attn16, wprojb, b_proj, out, ws_ok);
}

// Round 4
// 605.961 us; speedup vs baseline: 2.2940x; 1.0458x over previous
//
#include <hip/hip_runtime.h>
#include <stdint.h>

// ---------------- common helpers ----------------

typedef __attribute__((ext_vector_type(8))) short frag8;   // 8 bf16 (4 VGPRs), MFMA A/B operand
typedef __attribute__((ext_vector_type(4))) float frag4f;  // 4 fp32, MFMA C/D operand

__device__ __forceinline__ uint16_t f2bf(float f) {
  union { float f; uint32_t i; } x; x.f = f;
  uint32_t r = x.i + 0x7fffu + ((x.i >> 16) & 1u);  // round-to-nearest-even
  return (uint16_t)(r >> 16);
}

#define SCHED0() __builtin_amdgcn_sched_barrier(0)

// ---------------- kernel 0: fp32 -> bf16 conversion (RTNE), vectorized ----------------

__global__ __launch_bounds__(256)
void k_cvt(const float* __restrict__ src, uint16_t* __restrict__ dst, int n4, int ok)
{
  if (!ok) return;
  int i = blockIdx.x * 256 + threadIdx.x;
  const int stride = gridDim.x * 256;
  for (; i < n4; i += stride) {
    float4 v = ((const float4*)src)[i];
    ushort4 o;
    o.x = f2bf(v.x); o.y = f2bf(v.y); o.z = f2bf(v.z); o.w = f2bf(v.w);
    ((ushort4*)dst)[i] = o;
  }
}

// ---------------- kernel 1: fused roll + QKV GEMM + windowed attention ----------------
// grid: 512 M-tiles (128 rows = 8 batches) x 16 heads = 8192 blocks, 256 threads.
// GEMM loop: global_load_lds w16, dbuf, COUNTED vmcnt (T4: wait vmcnt(5) = only
// next-tile loads outstanding; current tile's loads were issued one full iter
// ago -> wait is ~free, prefetch stays in flight across the barrier).
// LDS 50.5 KB -> 3 blocks/CU (12 waves). p-buffer aliases dead q space; all
// Q/K fragment reads happen BEFORE softmax's p writes (extra barrier).

struct SmemEpi  { uint16_t q[128][68]; uint16_t k[128][68];    // 17 KB x2
                  uint16_t vT[64][132]; };                      // 16.5 KB
union Smem1 { uint8_t g[2][20480]; SmemEpi e; };                // 51,712 B -> 3 blocks/CU

__global__ __launch_bounds__(256, 3)
void k_qkv_attn(const uint16_t* __restrict__ xb, const uint16_t* __restrict__ wqkvb,
                const float* __restrict__ b_qkv, const float* __restrict__ rel_pos,
                uint16_t* __restrict__ attn16, int ws_ok)
{
  __shared__ Smem1 sm;
  const int bid  = blockIdx.x;
  const int h    = bid & 15;
  const int mt   = bid >> 4;
  const int t    = threadIdx.x;
  const int lane = t & 63;
  const int wv   = t >> 6;
  const int l15  = lane & 15;
  const int quad = lane >> 4;
  const int wr   = wv & 1;
  const int wc   = wv >> 1;

  if (!ws_ok) {  // ws too small: write zero attn slice (diagnostic), touch no ws
    #pragma unroll
    for (int i = 0; i < 32; ++i) {
      const int local = t + 256 * i;           // 0..8191
      const int row = local >> 6, col = local & 63;
      attn16[(mt * 128 + row) * 1024 + h * 64 + col] = 0;
    }
    return;
  }

  // ---- staging map: 20 chunks of 1 KB (64 lanes x 16 B). Chunks 0..7 = A
  // (128 rows x 64 B), chunks 8..19 = B (192 cols x 64 B). Wave wv stages 5
  // chunks. XOR slot swizzle (both-sides): LDS slot s' holds global slot
  // s = s' ^ ((row>>1)&3); source side collapses to slot_g per lane.
  const int slot_g = (lane & 3) ^ ((lane >> 3) & 3);
  const uint16_t* sp[5];
  int ldsoff[5];
  #pragma unroll
  for (int o = 0; o < 5; ++o) {
    const int c = wv * 5 + o;                  // 0..19
    const int rloc = c * 16 + (lane >> 2);     // tile-local row/col index
    if (c < 8) {                               // A: roll(-8 within 16) folded in
      const int g = mt * 128 + rloc;
      const int srow = (g & ~15) | ((g + 8) & 15);
      sp[o] = xb + srow * 512 + slot_g * 8;
    } else {                                   // B: q/k/v thirds of head h
      const int cb = rloc - 128;               // 0..191
      const int gc = (cb < 64) ? (h * 64 + cb)
                   : (cb < 128) ? (1024 + h * 64 + (cb - 64))
                                : (2048 + h * 64 + (cb - 128));
      sp[o] = wqkvb + gc * 512 + slot_g * 8;
    }
    ldsoff[o] = c * 1024;
  }

  frag4f acc[4][6];
  #pragma unroll
  for (int a = 0; a < 4; ++a)
    #pragma unroll
    for (int b = 0; b < 6; ++b) acc[a][b] = (frag4f)0.0f;

  auto STAGE = [&](int buf, int kk) {
    #pragma unroll
    for (int o = 0; o < 5; ++o)
      __builtin_amdgcn_global_load_lds(
          (const __attribute__((address_space(1))) void*)(sp[o] + kk * 32),
          (__attribute__((address_space(3))) void*)(sm.g[buf] + ldsoff[o]),
          16, 0, 0);
  };

  STAGE(0, 0);

  const int xq = quad ^ ((l15 >> 1) & 3);  // swizzled read slot
  for (int kk = 0; kk < 16; ++kk) {
    const int cur = kk & 1;
    if (kk < 15) {
      STAGE(cur ^ 1, kk + 1);              // issue next; stays in flight over MFMA
      SCHED0();
      asm volatile("s_waitcnt vmcnt(5)" ::: "memory");  // cur's 5 loads done
    } else {
      SCHED0();
      asm volatile("s_waitcnt vmcnt(0)" ::: "memory");
    }
    SCHED0();
    __builtin_amdgcn_s_barrier();          // all waves: cur fully staged
    SCHED0();

    const uint8_t* base = sm.g[cur];
    frag8 af[4], bf[6];
    #pragma unroll
    for (int rt = 0; rt < 4; ++rt)
      af[rt] = *(const frag8*)(base + (wr * 64 + rt * 16 + l15) * 64 + xq * 16);
    #pragma unroll
    for (int ct = 0; ct < 6; ++ct)
      bf[ct] = *(const frag8*)(base + 8192 + ((wc * 6 + ct) * 16 + l15) * 64 + xq * 16);
    #pragma unroll
    for (int rt = 0; rt < 4; ++rt)
      #pragma unroll
      for (int ct = 0; ct < 6; ++ct)
        acc[rt][ct] = __builtin_amdgcn_mfma_f32_16x16x32_bf16(af[rt], bf[ct], acc[rt][ct], 0, 0, 0);

    SCHED0();
    asm volatile("s_waitcnt lgkmcnt(0)" ::: "memory");  // this wave's ds_reads done
    SCHED0();
    __builtin_amdgcn_s_barrier();          // all waves done reading cur -> reusable
    SCHED0();
  }

  // ---- epilogue: +bias (fp32), stage Q, K row-major and V transposed ----
  #pragma unroll
  for (int ct = 0; ct < 6; ++ct) {
    const int C = (wc * 6 + ct) * 16 + l15;  // 0..191
    const int gc = (C < 64) ? (h * 64 + C)
                 : (C < 128) ? (1024 + h * 64 + (C - 64))
                             : (2048 + h * 64 + (C - 128));
    const float bias = b_qkv[gc];
    #pragma unroll
    for (int rt = 0; rt < 4; ++rt) {
      #pragma unroll
      for (int r = 0; r < 4; ++r) {
        const int row = wr * 64 + rt * 16 + quad * 4 + r;  // C-layout: row=quad*4+reg, col=l15
        const uint16_t val = f2bf(acc[rt][ct][r] + bias);
        if (C < 64)       sm.e.q[row][C] = val;
        else if (C < 128) sm.e.k[row][C - 64] = val;
        else              sm.e.vT[C - 128][row] = val;
      }
    }
  }
  __syncthreads();

  // ---- attention phase A: read Q/K frags + QK^T for BOTH windows first
  // (p will alias q's storage, so all q reads must precede p writes) ----
  const float scl = 0.125f;  // 64^-0.5
  frag8 qa0[2], qa1[2], kb0[2], kb1[2];
  frag4f s2[2];
  #pragma unroll
  for (int bbi = 0; bbi < 2; ++bbi) {
    const int bb = wv * 2 + bbi;
    qa0[bbi] = *(const frag8*)&sm.e.q[bb * 16 + l15][quad * 8];
    qa1[bbi] = *(const frag8*)&sm.e.q[bb * 16 + l15][32 + quad * 8];
    kb0[bbi] = *(const frag8*)&sm.e.k[bb * 16 + l15][quad * 8];
    kb1[bbi] = *(const frag8*)&sm.e.k[bb * 16 + l15][32 + quad * 8];
  }
  #pragma unroll
  for (int bbi = 0; bbi < 2; ++bbi) {
    frag4f s = (frag4f)0.0f;
    s = __builtin_amdgcn_mfma_f32_16x16x32_bf16(qa0[bbi], kb0[bbi], s, 0, 0, 0);
    s = __builtin_amdgcn_mfma_f32_16x16x32_bf16(qa1[bbi], kb1[bbi], s, 0, 0, 0);
    s2[bbi] = s;
  }
  __syncthreads();  // all q reads complete; q storage now reusable for p

  // ---- softmax (mask + rel-pos bias), write P into p (aliases q) ----
  uint16_t (*pp)[16][20] = (uint16_t (*)[16][20])sm.e.q;  // 8x16x20x2B = 5.1 KB
  #pragma unroll
  for (int bbi = 0; bbi < 2; ++bbi) {
    const int bb = wv * 2 + bbi;
    const int j = l15;
    #pragma unroll
    for (int r = 0; r < 4; ++r) {
      const int i = quad * 4 + r;
      const int r0 = (i >> 2) - (j >> 2) + 3;
      const int r1 = (i & 3) - (j & 3) + 3;
      const float bias = rel_pos[h * 49 + r0 * 7 + r1];
      const bool msk = ((h >= 14) && (((i >> 2) < 2) != ((j >> 2) < 2))) ||
                       ((h & 1)  && (((i & 3) < 2) != ((j & 3) < 2)));
      float v = msk ? -1e30f : (s2[bbi][r] * scl + bias);
      float m = v;
      m = fmaxf(m, __shfl_xor(m, 1));
      m = fmaxf(m, __shfl_xor(m, 2));
      m = fmaxf(m, __shfl_xor(m, 4));
      m = fmaxf(m, __shfl_xor(m, 8));
      float e = __expf(v - m);
      float su = e;
      su += __shfl_xor(su, 1);
      su += __shfl_xor(su, 2);
      su += __shfl_xor(su, 4);
      su += __shfl_xor(su, 8);
      pp[bb][i][j] = f2bf(e / su);
    }
  }
  __syncthreads();

  // ---- O = P V; K=32 MFMA with k>=16 half of A zeroed ----
  #pragma unroll
  for (int bbi = 0; bbi < 2; ++bbi) {
    const int bb = wv * 2 + bbi;
    frag8 ap;
    if (quad < 2) ap = *(const frag8*)&pp[bb][l15][quad * 8];
    else          ap = (frag8)0;
    #pragma unroll
    for (int dt = 0; dt < 4; ++dt) {
      frag8 bv = *(const frag8*)&sm.e.vT[dt * 16 + l15][bb * 16 + (quad & 1) * 8];
      frag4f o = (frag4f)0.0f;
      o = __builtin_amdgcn_mfma_f32_16x16x32_bf16(ap, bv, o, 0, 0, 0);
      #pragma unroll
      for (int r = 0; r < 4; ++r) {
        const int grow = mt * 128 + bb * 16 + quad * 4 + r;
        attn16[grow * 1024 + h * 64 + dt * 16 + l15] = f2bf(o[r]);
      }
    }
  }
}

// ---------------- kernel 2: projection GEMM (M=65536, K=1024, N=512) + bias, fp32 out ----------------
// In-place constraint: out fp32 row r occupies the same 2048 bytes as attn16 bf16
// row r, so a block must own COMPLETE rows (read all K before writing any col).
// grid 1024 blocks x 512 threads (8 waves), tile 64 rows x 512 cols, BK=32,
// global_load_lds dbuf with COUNTED vmcnt (T4) + XOR slot swizzle.

__global__ __launch_bounds__(512, 4)
void k_proj(const uint16_t* __restrict__ attn16, const uint16_t* __restrict__ wprojb,
            const float* __restrict__ b_proj, float* __restrict__ out, int ws_ok)
{
  __shared__ uint8_t smraw[2 * 36864];  // 2 x (A 4096 B + B 32768 B) = 72 KB
  const int mt   = blockIdx.x;          // 0..1023, rows [mt*64, mt*64+64)
  const int t    = threadIdx.x;
  const int lane = t & 63;
  const int wv   = t >> 6;              // 0..7
  const int l15  = lane & 15;
  const int quad = lane >> 4;

  if (!ws_ok) {  // diagnostic fallback: bias only
    for (int i = t; i < 64 * 512; i += 512) {
      const int row = i >> 9, col = i & 511;
      out[(mt * 64 + row) * 512 + col] = b_proj[col];
    }
    return;
  }

  // ---- staging map: 36 chunks of 1 KB. Chunks 0..3 = A (64 rows x 64 B),
  // chunks 4..35 = B (512 cols x 64 B). XOR slot swizzle on the source side.
  const int cnt = (wv < 4) ? 5 : 4;
  const int c0  = (wv < 4) ? wv * 5 : 20 + (wv - 4) * 4;
  const int slot_g = (lane & 3) ^ ((lane >> 3) & 3);

  const uint16_t* gp[5];
  int lds_off[5];
  #pragma unroll
  for (int o = 0; o < 5; ++o) {
    int c = c0 + o;
    if (c > 35) c = 35;                          // clamp unused slot (never issued)
    const int rloc = c * 16 + (lane >> 2);       // tile-local row/col
    if (c < 4) {                                 // A region: rows 0..63
      gp[o] = attn16 + (size_t)(mt * 64 + rloc) * 1024 + slot_g * 8;
    } else {                                     // B region: cols 0..511
      gp[o] = wprojb + (size_t)(rloc - 64) * 1024 + slot_g * 8;
    }
    lds_off[o] = (c0 + o) * 1024;
  }

  frag4f acc[4][4];
  #pragma unroll
  for (int a = 0; a < 4; ++a)
    #pragma unroll
    for (int b = 0; b < 4; ++b) acc[a][b] = (frag4f)0.0f;

  auto STAGE = [&](int buf, int kk) {
    #pragma unroll
    for (int o = 0; o < 5; ++o)
      if (o < cnt)
        __builtin_amdgcn_global_load_lds(
            (const __attribute__((address_space(1))) void*)(gp[o] + kk * 32),
            (__attribute__((address_space(3))) void*)(smraw + buf * 36864 + lds_off[o]),
            16, 0, 0);
  };

  STAGE(0, 0);

  const int xq = quad ^ ((l15 >> 1) & 3);  // swizzled read slot
  for (int kk = 0; kk < 32; ++kk) {
    const int cur = kk & 1;
    if (kk < 31) {
      STAGE(cur ^ 1, kk + 1);              // next tile flies under compute
      SCHED0();
      if (wv < 4) asm volatile("s_waitcnt vmcnt(5)" ::: "memory");
      else        asm volatile("s_waitcnt vmcnt(4)" ::: "memory");
    } else {
      SCHED0();
      asm volatile("s_waitcnt vmcnt(0)" ::: "memory");
    }
    SCHED0();
    __builtin_amdgcn_s_barrier();          // all waves: cur fully staged
    SCHED0();

    const uint16_t* As = (const uint16_t*)(smraw + cur * 36864);
    const uint16_t* Bs = (const uint16_t*)(smraw + cur * 36864 + 4096);
    frag8 af[4];
    #pragma unroll
    for (int rt = 0; rt < 4; ++rt)
      af[rt] = *(const frag8*)(As + (rt * 16 + l15) * 32 + xq * 8);
    #pragma unroll
    for (int ct = 0; ct < 4; ++ct) {
      frag8 bfr = *(const frag8*)(Bs + (wv * 64 + ct * 16 + l15) * 32 + xq * 8);
      #pragma unroll
      for (int rt = 0; rt < 4; ++rt)
        acc[rt][ct] = __builtin_amdgcn_mfma_f32_16x16x32_bf16(af[rt], bfr, acc[rt][ct], 0, 0, 0);
    }

    SCHED0();
    asm volatile("s_waitcnt lgkmcnt(0)" ::: "memory");  // this wave's ds_reads done
    SCHED0();
    __builtin_amdgcn_s_barrier();          // all waves done reading cur -> reusable
    SCHED0();
  }

  // ---- epilogue: + bias, fp32 stores (after final barrier -> all A reads done)
  #pragma unroll
  for (int ct = 0; ct < 4; ++ct) {
    const int gcol = wv * 64 + ct * 16 + l15;
    const float bias = b_proj[gcol];
    #pragma unroll
    for (int rt = 0; rt < 4; ++rt) {
      #pragma unroll
      for (int r = 0; r < 4; ++r) {
        const int grow = mt * 64 + rt * 16 + quad * 4 + r;  // C-layout: row=quad*4+reg
        out[grow * 512 + gcol] = acc[rt][ct][r] + bias;
      }
    }
  }
}

// ---------------- launch ----------------

extern "C" void kernel_launch(void* const* d_in, const int* in_sizes, int n_in,
                              void* d_out, int out_size, void* d_ws, size_t ws_size,
                              hipStream_t stream) {
  const float* x      = (const float*)d_in[0];   // (4096,16,512) fp32
  const float* w_qkv  = (const float*)d_in[1];   // (3072,512)    fp32
  const float* b_qkv  = (const float*)d_in[2];   // (3072,)       fp32
  const float* w_proj = (const float*)d_in[3];   // (512,1024)    fp32
  const float* b_proj = (const float*)d_in[4];   // (512,)        fp32
  const float* rel    = (const float*)d_in[5];   // (16,7,7)      fp32

  // ws layout (bf16): x 33,554,432 | w_qkv 1,572,864 | w_proj 524,288 el
  uint16_t* xb     = (uint16_t*)d_ws;
  uint16_t* wqkvb  = xb + 33554432;
  uint16_t* wprojb = wqkvb + 1572864;
  const size_t ws_need = (size_t)(33554432 + 1572864 + 524288) * 2;
  const int ws_ok = (ws_size >= ws_need) ? 1 : 0;

  // d_out bytes: phase 1 = bf16 attn (65536 x 1024 x 2B), phase 2 = fp32 out (65536 x 512 x 4B)
  uint16_t* attn16 = (uint16_t*)d_out;
  float*    out    = (float*)d_out;

  k_cvt<<<dim3(4096), dim3(256), 0, stream>>>(x,      xb,     33554432 / 4, ws_ok);
  k_cvt<<<dim3(1536), dim3(256), 0, stream>>>(w_qkv,  wqkvb,  1572864 / 4,  ws_ok);
  k_cvt<<<dim3(512),  dim3(256), 0, stream>>>(w_proj, wprojb, 524288 / 4,   ws_ok);
  k_qkv_attn<<<dim3(512 * 16), dim3(256), 0, stream>>>(xb, wqkvb, b_qkv, rel, attn16, ws_ok);
  k_proj    <<<dim3(1024),     dim3(512), 0, stream>>>(attn16, wprojb, b_proj, out, ws_ok);
}

// Round 5
// 603.516 us; speedup vs baseline: 2.3033x; 1.0041x over previous
//
#include <hip/hip_runtime.h>
#include <stdint.h>

// ---------------- common helpers ----------------

typedef __attribute__((ext_vector_type(8))) short frag8;   // 8 bf16 (4 VGPRs), MFMA A/B operand
typedef __attribute__((ext_vector_type(4))) float frag4f;  // 4 fp32, MFMA C/D operand

__device__ __forceinline__ uint16_t f2bf(float f) {
  union { float f; uint32_t i; } x; x.f = f;
  uint32_t r = x.i + 0x7fffu + ((x.i >> 16) & 1u);  // round-to-nearest-even
  return (uint16_t)(r >> 16);
}

#define SCHED0() __builtin_amdgcn_sched_barrier(0)

// ---------------- kernel 0: fp32 -> bf16 conversion (RTNE), vectorized ----------------

__global__ __launch_bounds__(256)
void k_cvt(const float* __restrict__ src, uint16_t* __restrict__ dst, int n4, int ok)
{
  if (!ok) return;
  int i = blockIdx.x * 256 + threadIdx.x;
  const int stride = gridDim.x * 256;
  for (; i < n4; i += stride) {
    float4 v = ((const float4*)src)[i];
    ushort4 o;
    o.x = f2bf(v.x); o.y = f2bf(v.y); o.z = f2bf(v.z); o.w = f2bf(v.w);
    ((ushort4*)dst)[i] = o;
  }
}

// ---------------- kernel 1: fused roll + QKV GEMM + windowed attention ----------------
// grid: 512 M-tiles (128 rows = 8 batches) x 16 heads = 8192 blocks, 256 threads.
// T1 XCD swizzle: dispatch round-robins blockIdx%8 across XCDs; remap
// logical = (bid&7)*1024 + (bid>>3) so XCD x owns mt in [x*64,(x+1)*64) x all
// 16 heads -> each A-tile fetched by exactly ONE XCD's L2 (16x head reuse),
// w_qkv (3 MB bf16) L2-resident per XCD. 8192 % 8 == 0 -> bijective.
// GEMM loop: global_load_lds w16, dbuf, counted vmcnt (T4), XOR slot swizzle.
// LDS 50.5 KB -> 3 blocks/CU.

struct SmemEpi  { uint16_t q[128][68]; uint16_t k[128][68];    // 17 KB x2
                  uint16_t vT[64][132]; };                      // 16.5 KB
union Smem1 { uint8_t g[2][20480]; SmemEpi e; };                // 51,712 B -> 3 blocks/CU

__global__ __launch_bounds__(256, 3)
void k_qkv_attn(const uint16_t* __restrict__ xb, const uint16_t* __restrict__ wqkvb,
                const float* __restrict__ b_qkv, const float* __restrict__ rel_pos,
                uint16_t* __restrict__ attn16, int ws_ok)
{
  __shared__ Smem1 sm;
  const int bid  = blockIdx.x;
  const int lgc  = ((bid & 7) << 10) | (bid >> 3);  // XCD-contiguous logical id
  const int h    = lgc & 15;
  const int mt   = lgc >> 4;
  const int t    = threadIdx.x;
  const int lane = t & 63;
  const int wv   = t >> 6;
  const int l15  = lane & 15;
  const int quad = lane >> 4;
  const int wr   = wv & 1;
  const int wc   = wv >> 1;

  if (!ws_ok) {  // ws too small: write zero attn slice (diagnostic), touch no ws
    #pragma unroll
    for (int i = 0; i < 32; ++i) {
      const int local = t + 256 * i;           // 0..8191
      const int row = local >> 6, col = local & 63;
      attn16[(mt * 128 + row) * 1024 + h * 64 + col] = 0;
    }
    return;
  }

  // ---- staging map: 20 chunks of 1 KB (64 lanes x 16 B). Chunks 0..7 = A
  // (128 rows x 64 B), chunks 8..19 = B (192 cols x 64 B). Wave wv stages 5
  // chunks. XOR slot swizzle (both-sides): LDS slot s' holds global slot
  // s = s' ^ ((row>>1)&3); source side collapses to slot_g per lane.
  const int slot_g = (lane & 3) ^ ((lane >> 3) & 3);
  const uint16_t* sp[5];
  int ldsoff[5];
  #pragma unroll
  for (int o = 0; o < 5; ++o) {
    const int c = wv * 5 + o;                  // 0..19
    const int rloc = c * 16 + (lane >> 2);     // tile-local row/col index
    if (c < 8) {                               // A: roll(-8 within 16) folded in
      const int g = mt * 128 + rloc;
      const int srow = (g & ~15) | ((g + 8) & 15);
      sp[o] = xb + srow * 512 + slot_g * 8;
    } else {                                   // B: q/k/v thirds of head h
      const int cb = rloc - 128;               // 0..191
      const int gc = (cb < 64) ? (h * 64 + cb)
                   : (cb < 128) ? (1024 + h * 64 + (cb - 64))
                                : (2048 + h * 64 + (cb - 128));
      sp[o] = wqkvb + gc * 512 + slot_g * 8;
    }
    ldsoff[o] = c * 1024;
  }

  frag4f acc[4][6];
  #pragma unroll
  for (int a = 0; a < 4; ++a)
    #pragma unroll
    for (int b = 0; b < 6; ++b) acc[a][b] = (frag4f)0.0f;

  auto STAGE = [&](int buf, int kk) {
    #pragma unroll
    for (int o = 0; o < 5; ++o)
      __builtin_amdgcn_global_load_lds(
          (const __attribute__((address_space(1))) void*)(sp[o] + kk * 32),
          (__attribute__((address_space(3))) void*)(sm.g[buf] + ldsoff[o]),
          16, 0, 0);
  };

  STAGE(0, 0);

  const int xq = quad ^ ((l15 >> 1) & 3);  // swizzled read slot
  for (int kk = 0; kk < 16; ++kk) {
    const int cur = kk & 1;
    if (kk < 15) {
      STAGE(cur ^ 1, kk + 1);              // issue next; stays in flight over MFMA
      SCHED0();
      asm volatile("s_waitcnt vmcnt(5)" ::: "memory");  // cur's 5 loads done
    } else {
      SCHED0();
      asm volatile("s_waitcnt vmcnt(0)" ::: "memory");
    }
    SCHED0();
    __builtin_amdgcn_s_barrier();          // all waves: cur fully staged
    SCHED0();

    const uint8_t* base = sm.g[cur];
    frag8 af[4], bf[6];
    #pragma unroll
    for (int rt = 0; rt < 4; ++rt)
      af[rt] = *(const frag8*)(base + (wr * 64 + rt * 16 + l15) * 64 + xq * 16);
    #pragma unroll
    for (int ct = 0; ct < 6; ++ct)
      bf[ct] = *(const frag8*)(base + 8192 + ((wc * 6 + ct) * 16 + l15) * 64 + xq * 16);
    #pragma unroll
    for (int rt = 0; rt < 4; ++rt)
      #pragma unroll
      for (int ct = 0; ct < 6; ++ct)
        acc[rt][ct] = __builtin_amdgcn_mfma_f32_16x16x32_bf16(af[rt], bf[ct], acc[rt][ct], 0, 0, 0);

    SCHED0();
    asm volatile("s_waitcnt lgkmcnt(0)" ::: "memory");  // this wave's ds_reads done
    SCHED0();
    __builtin_amdgcn_s_barrier();          // all waves done reading cur -> reusable
    SCHED0();
  }

  // ---- epilogue: +bias (fp32), stage Q, K row-major and V transposed ----
  #pragma unroll
  for (int ct = 0; ct < 6; ++ct) {
    const int C = (wc * 6 + ct) * 16 + l15;  // 0..191
    const int gc = (C < 64) ? (h * 64 + C)
                 : (C < 128) ? (1024 + h * 64 + (C - 64))
                             : (2048 + h * 64 + (C - 128));
    const float bias = b_qkv[gc];
    #pragma unroll
    for (int rt = 0; rt < 4; ++rt) {
      #pragma unroll
      for (int r = 0; r < 4; ++r) {
        const int row = wr * 64 + rt * 16 + quad * 4 + r;  // C-layout: row=quad*4+reg, col=l15
        const uint16_t val = f2bf(acc[rt][ct][r] + bias);
        if (C < 64)       sm.e.q[row][C] = val;
        else if (C < 128) sm.e.k[row][C - 64] = val;
        else              sm.e.vT[C - 128][row] = val;
      }
    }
  }
  __syncthreads();

  // ---- attention phase A: read Q/K frags + QK^T for BOTH windows first
  // (p will alias q's storage, so all q reads must precede p writes) ----
  const float scl = 0.125f;  // 64^-0.5
  frag8 qa0[2], qa1[2], kb0[2], kb1[2];
  frag4f s2[2];
  #pragma unroll
  for (int bbi = 0; bbi < 2; ++bbi) {
    const int bb = wv * 2 + bbi;
    qa0[bbi] = *(const frag8*)&sm.e.q[bb * 16 + l15][quad * 8];
    qa1[bbi] = *(const frag8*)&sm.e.q[bb * 16 + l15][32 + quad * 8];
    kb0[bbi] = *(const frag8*)&sm.e.k[bb * 16 + l15][quad * 8];
    kb1[bbi] = *(const frag8*)&sm.e.k[bb * 16 + l15][32 + quad * 8];
  }
  #pragma unroll
  for (int bbi = 0; bbi < 2; ++bbi) {
    frag4f s = (frag4f)0.0f;
    s = __builtin_amdgcn_mfma_f32_16x16x32_bf16(qa0[bbi], kb0[bbi], s, 0, 0, 0);
    s = __builtin_amdgcn_mfma_f32_16x16x32_bf16(qa1[bbi], kb1[bbi], s, 0, 0, 0);
    s2[bbi] = s;
  }
  __syncthreads();  // all q reads complete; q storage now reusable for p

  // ---- softmax (mask + rel-pos bias), write P into p (aliases q) ----
  uint16_t (*pp)[16][20] = (uint16_t (*)[16][20])sm.e.q;  // 8x16x20x2B = 5.1 KB
  #pragma unroll
  for (int bbi = 0; bbi < 2; ++bbi) {
    const int bb = wv * 2 + bbi;
    const int j = l15;
    #pragma unroll
    for (int r = 0; r < 4; ++r) {
      const int i = quad * 4 + r;
      const int r0 = (i >> 2) - (j >> 2) + 3;
      const int r1 = (i & 3) - (j & 3) + 3;
      const float bias = rel_pos[h * 49 + r0 * 7 + r1];
      const bool msk = ((h >= 14) && (((i >> 2) < 2) != ((j >> 2) < 2))) ||
                       ((h & 1)  && (((i & 3) < 2) != ((j & 3) < 2)));
      float v = msk ? -1e30f : (s2[bbi][r] * scl + bias);
      float m = v;
      m = fmaxf(m, __shfl_xor(m, 1));
      m = fmaxf(m, __shfl_xor(m, 2));
      m = fmaxf(m, __shfl_xor(m, 4));
      m = fmaxf(m, __shfl_xor(m, 8));
      float e = __expf(v - m);
      float su = e;
      su += __shfl_xor(su, 1);
      su += __shfl_xor(su, 2);
      su += __shfl_xor(su, 4);
      su += __shfl_xor(su, 8);
      pp[bb][i][j] = f2bf(e / su);
    }
  }
  __syncthreads();

  // ---- O = P V; K=32 MFMA with k>=16 half of A zeroed ----
  #pragma unroll
  for (int bbi = 0; bbi < 2; ++bbi) {
    const int bb = wv * 2 + bbi;
    frag8 ap;
    if (quad < 2) ap = *(const frag8*)&pp[bb][l15][quad * 8];
    else          ap = (frag8)0;
    #pragma unroll
    for (int dt = 0; dt < 4; ++dt) {
      frag8 bv = *(const frag8*)&sm.e.vT[dt * 16 + l15][bb * 16 + (quad & 1) * 8];
      frag4f o = (frag4f)0.0f;
      o = __builtin_amdgcn_mfma_f32_16x16x32_bf16(ap, bv, o, 0, 0, 0);
      #pragma unroll
      for (int r = 0; r < 4; ++r) {
        const int grow = mt * 128 + bb * 16 + quad * 4 + r;
        attn16[grow * 1024 + h * 64 + dt * 16 + l15] = f2bf(o[r]);
      }
    }
  }
}

// ---------------- kernel 2: projection GEMM (M=65536, K=1024, N=512) + bias, fp32 out ----------------
// In-place constraint: out fp32 row r occupies the same 2048 bytes as attn16 bf16
// row r, so a block must own COMPLETE rows (read all K before writing any col).
// Structure (round-3 verified-best, ~116 us implied; round-4's asm-barrier
// variant regressed +14 us -> reverted): grid 1024 blocks x 512 threads,
// tile 64 x 512, BK=32, global_load_lds dbuf, ONE __syncthreads per K-step
// (its vmcnt(0)+lgkm drain = exactly the ordering needed), XOR slot swizzle.

__global__ __launch_bounds__(512, 4)
void k_proj(const uint16_t* __restrict__ attn16, const uint16_t* __restrict__ wprojb,
            const float* __restrict__ b_proj, float* __restrict__ out, int ws_ok)
{
  __shared__ uint8_t smraw[2 * 36864];  // 2 x (A 4096 B + B 32768 B) = 72 KB
  const int mt   = blockIdx.x;          // 0..1023, rows [mt*64, mt*64+64)
  const int t    = threadIdx.x;
  const int lane = t & 63;
  const int wv   = t >> 6;              // 0..7
  const int l15  = lane & 15;
  const int quad = lane >> 4;

  if (!ws_ok) {  // diagnostic fallback: bias only
    for (int i = t; i < 64 * 512; i += 512) {
      const int row = i >> 9, col = i & 511;
      out[(mt * 64 + row) * 512 + col] = b_proj[col];
    }
    return;
  }

  // ---- staging map: 36 chunks of 1 KB. Chunks 0..3 = A (64 rows x 64 B),
  // chunks 4..35 = B (512 cols x 64 B). XOR slot swizzle on the source side.
  const int cnt = (wv < 4) ? 5 : 4;
  const int c0  = (wv < 4) ? wv * 5 : 20 + (wv - 4) * 4;
  const int slot_g = (lane & 3) ^ ((lane >> 3) & 3);

  const uint16_t* gp[5];
  int lds_off[5];
  #pragma unroll
  for (int o = 0; o < 5; ++o) {
    int c = c0 + o;
    if (c > 35) c = 35;                          // clamp unused slot (never issued)
    const int rloc = c * 16 + (lane >> 2);       // tile-local row/col
    if (c < 4) {                                 // A region: rows 0..63
      gp[o] = attn16 + (size_t)(mt * 64 + rloc) * 1024 + slot_g * 8;
    } else {                                     // B region: cols 0..511
      gp[o] = wprojb + (size_t)(rloc - 64) * 1024 + slot_g * 8;
    }
    lds_off[o] = (c0 + o) * 1024;
  }

  frag4f acc[4][4];
  #pragma unroll
  for (int a = 0; a < 4; ++a)
    #pragma unroll
    for (int b = 0; b < 4; ++b) acc[a][b] = (frag4f)0.0f;

  auto STAGE = [&](int buf, int kk) {
    #pragma unroll
    for (int o = 0; o < 5; ++o)
      if (o < cnt)
        __builtin_amdgcn_global_load_lds(
            (const __attribute__((address_space(1))) void*)(gp[o] + kk * 32),
            (__attribute__((address_space(3))) void*)(smraw + buf * 36864 + lds_off[o]),
            16, 0, 0);
  };

  STAGE(0, 0);
  __syncthreads();  // drains vmcnt(0): buf0 ready

  const int xq = quad ^ ((l15 >> 1) & 3);  // swizzled read slot
  for (int kk = 0; kk < 32; ++kk) {
    const int cur = kk & 1;
    if (kk < 31) STAGE(cur ^ 1, kk + 1);  // issue next tile; flies under compute

    const uint16_t* As = (const uint16_t*)(smraw + cur * 36864);
    const uint16_t* Bs = (const uint16_t*)(smraw + cur * 36864 + 4096);
    frag8 af[4];
    #pragma unroll
    for (int rt = 0; rt < 4; ++rt)
      af[rt] = *(const frag8*)(As + (rt * 16 + l15) * 32 + xq * 8);
    #pragma unroll
    for (int ct = 0; ct < 4; ++ct) {
      frag8 bfr = *(const frag8*)(Bs + (wv * 64 + ct * 16 + l15) * 32 + xq * 8);
      #pragma unroll
      for (int rt = 0; rt < 4; ++rt)
        acc[rt][ct] = __builtin_amdgcn_mfma_f32_16x16x32_bf16(af[rt], bfr, acc[rt][ct], 0, 0, 0);
    }
    __syncthreads();  // vmcnt(0)+lgkm drain: next buf ready; all waves done reading cur
  }

  // ---- epilogue: + bias, fp32 stores (after final barrier -> all A reads done)
  #pragma unroll
  for (int ct = 0; ct < 4; ++ct) {
    const int gcol = wv * 64 + ct * 16 + l15;
    const float bias = b_proj[gcol];
    #pragma unroll
    for (int rt = 0; rt < 4; ++rt) {
      #pragma unroll
      for (int r = 0; r < 4; ++r) {
        const int grow = mt * 64 + rt * 16 + quad * 4 + r;  // C-layout: row=quad*4+reg
        out[grow * 512 + gcol] = acc[rt][ct][r] + bias;
      }
    }
  }
}

// ---------------- launch ----------------

extern "C" void kernel_launch(void* const* d_in, const int* in_sizes, int n_in,
                              void* d_out, int out_size, void* d_ws, size_t ws_size,
                              hipStream_t stream) {
  const float* x      = (const float*)d_in[0];   // (4096,16,512) fp32
  const float* w_qkv  = (const float*)d_in[1];   // (3072,512)    fp32
  const float* b_qkv  = (const float*)d_in[2];   // (3072,)       fp32
  const float* w_proj = (const float*)d_in[3];   // (512,1024)    fp32
  const float* b_proj = (const float*)d_in[4];   // (512,)        fp32
  const float* rel    = (const float*)d_in[5];   // (16,7,7)      fp32

  // ws layout (bf16): x 33,554,432 | w_qkv 1,572,864 | w_proj 524,288 el
  uint16_t* xb     = (uint16_t*)d_ws;
  uint16_t* wqkvb  = xb + 33554432;
  uint16_t* wprojb = wqkvb + 1572864;
  const size_t ws_need = (size_t)(33554432 + 1572864 + 524288) * 2;
  const int ws_ok = (ws_size >= ws_need) ? 1 : 0;

  // d_out bytes: phase 1 = bf16 attn (65536 x 1024 x 2B), phase 2 = fp32 out (65536 x 512 x 4B)
  uint16_t* attn16 = (uint16_t*)d_out;
  float*    out    = (float*)d_out;

  k_cvt<<<dim3(4096), dim3(256), 0, stream>>>(x,      xb,     33554432 / 4, ws_ok);
  k_cvt<<<dim3(1536), dim3(256), 0, stream>>>(w_qkv,  wqkvb,  1572864 / 4,  ws_ok);
  k_cvt<<<dim3(512),  dim3(256), 0, stream>>>(w_proj, wprojb, 524288 / 4,   ws_ok);
  k_qkv_attn<<<dim3(512 * 16), dim3(256), 0, stream>>>(xb, wqkvb, b_qkv, rel, attn16, ws_ok);
  k_proj    <<<dim3(1024),     dim3(512), 0, stream>>>(attn16, wprojb, b_proj, out, ws_ok);
}